// Round 5
// baseline (911.769 us; speedup 1.0000x reference)
//
#include <hip/hip_runtime.h>
#include <hip/hip_bf16.h>

#define BB 8
#define CC 128
#define HH 128
#define WW 128
#define HW (HH*WW)
#define EE 4
#define EPSL 1e-6f

typedef __attribute__((ext_vector_type(8))) short bf16x8;
typedef __attribute__((ext_vector_type(4))) float f32x4;

__device__ inline float b2f(unsigned short u){
  union { unsigned int i; float f; } v; v.i = ((unsigned int)u)<<16; return v.f;
}
__device__ inline unsigned short f2b(float f){
  union { float f; unsigned int i; } v; v.f = f;
  unsigned int x = v.i;
  return (unsigned short)((x + 0x7fffu + ((x>>16)&1u)) >> 16);
}

// ---- K1: LayerNorm over C per pixel; xin stored [b][p][c] bf16 (channel-contig)
__global__ __launch_bounds__(256) void k_ln(
    const float* __restrict__ x, const float* __restrict__ gamma,
    const float* __restrict__ beta, unsigned short* __restrict__ xin,
    float* __restrict__ feat_sum) {
  int b = blockIdx.y;
  int p = blockIdx.x*256 + threadIdx.x;
  const float* xb = x + (size_t)b*CC*HW + p;
  float s=0.f, s2=0.f;
  for (int c=0;c<CC;c++){ float v = xb[(size_t)c*HW]; s+=v; s2+=v*v; }
  float mu = s*(1.f/CC);
  float var = s2*(1.f/CC) - mu*mu;
  float rs = rsqrtf(var + EPSL);
  __shared__ float lfeat[CC];
  for (int c=threadIdx.x;c<CC;c+=256) lfeat[c]=0.f;
  __syncthreads();
  int lane = threadIdx.x & 63;
  unsigned short* xo = xin + ((size_t)b*HW + p)*CC;
  for (int c0=0;c0<CC;c0+=8){
    union { bf16x8 v; unsigned short s[8]; } pk;
    float vs[8];
    #pragma unroll
    for (int j=0;j<8;j++){
      float v = (xb[(size_t)(c0+j)*HW]-mu)*rs*gamma[c0+j]+beta[c0+j];
      vs[j]=v; pk.s[j]=f2b(v);
    }
    *(bf16x8*)(xo + c0) = pk.v;
    #pragma unroll
    for (int j=0;j<8;j++){
      float r = vs[j];
      for (int o=32;o>0;o>>=1) r += __shfl_down(r, o);
      if (lane==0) atomicAdd(&lfeat[c0+j], r);
    }
  }
  __syncthreads();
  for (int c=threadIdx.x;c<CC;c+=256) atomicAdd(&feat_sum[b*CC+c], lfeat[c]);
}

// ---- K2: router (1 block) ------------------------------------------------------
__global__ __launch_bounds__(256) void k_router(
    const float* __restrict__ feat_sum, const float* __restrict__ prompt,
    const float* __restrict__ rw, const float* __restrict__ rb,
    const float* __restrict__ b2, const float* __restrict__ pw,
    const float* __restrict__ pb,
    int* __restrict__ eidx, float* __restrict__ wgt, float* __restrict__ bias_out) {
  __shared__ float logits[BB][EE];
  __shared__ float gate[BB][EE];
  __shared__ float cb[BB][CC];
  int t = threadIdx.x;
  if (t < BB*EE) {
    int b = t/EE, e = t%EE;
    float acc = rb[e];
    for (int c=0;c<CC;c++) acc += (feat_sum[b*CC+c]*(1.f/HW))*rw[c*EE+e];
    for (int c=0;c<CC;c++) acc += prompt[b*CC+c]*rw[(CC+c)*EE+e];
    logits[b][e]=acc;
  }
  __syncthreads();
  if (t < BB) {
    int b=t;
    float m=-1e30f;
    for(int e=0;e<EE;e++) m=fmaxf(m,logits[b][e]);
    float s=0.f, pr[EE];
    for(int e=0;e<EE;e++){ pr[e]=__expf(logits[b][e]-m); s+=pr[e]; }
    for(int e=0;e<EE;e++){ pr[e]/=s; gate[b][e]=0.f; }
    int i1=0; for(int e=1;e<EE;e++) if (pr[e]>pr[i1]) i1=e;
    int i2=-1; for(int e=0;e<EE;e++){ if(e==i1) continue; if(i2<0||pr[e]>pr[i2]) i2=e; }
    eidx[b*2]=i1; eidx[b*2+1]=i2;
    wgt[b*2]=pr[i1]; wgt[b*2+1]=pr[i2];
    gate[b][i1]=pr[i1]; gate[b][i2]=pr[i2];
  }
  __syncthreads();
  for (int i=t;i<BB*CC;i+=256){
    int b=i/CC, c=i%CC;
    float a=0.f;
    for(int e=0;e<EE;e++) a += gate[b][e]*b2[e*CC+c];
    cb[b][c]=a;
  }
  __syncthreads();
  for (int i=t;i<BB*CC;i+=256){
    int b=i/CC, o=i%CC;
    float a=pb[o];
    for (int c=0;c<CC;c++) a += pw[o*CC+c]*cb[b][c];
    bias_out[b*CC+o]=a;
  }
}

// ---- K3: prep: w2p[e] = bf16(pw @ w2[e]); w1b[e] = bf16(w1[e]) -----------------
__global__ __launch_bounds__(128) void k_prep(
    const float* __restrict__ pw, const float* __restrict__ w2,
    const float* __restrict__ w1,
    unsigned short* __restrict__ w2p, unsigned short* __restrict__ w1b){
  int eo = blockIdx.x; int e = eo/CC, o = eo%CC;
  int c = threadIdx.x;
  float a=0.f;
  for (int m=0;m<CC;m++) a += pw[o*CC+m]*w2[((size_t)e*CC+m)*CC+c];
  w2p[((size_t)e*CC+o)*CC+c] = f2b(a);
  w1b[((size_t)e*CC+o)*CC+c] = f2b(w1[((size_t)e*CC+o)*CC+c]);
}

// ---- K3b: w2s[bk] = bf16(wgt[bk] * w2p[e[bk]]) (gate baked into weights) -------
__global__ __launch_bounds__(256) void k_scalew2(
    const unsigned short* __restrict__ w2p, const int* __restrict__ eidx,
    const float* __restrict__ wgt, unsigned short* __restrict__ w2s){
  int bk = blockIdx.y;
  int e = eidx[bk]; float wv = wgt[bk];
  int i = blockIdx.x*256 + threadIdx.x;
  const unsigned short* src = w2p + (size_t)e*CC*CC;
  w2s[(size_t)bk*CC*CC + i] = f2b(wv * b2f(src[i]));
}

// ---- K4: GEMM1 (MFMA bf16): t1[bk][p][o] = w1b[e] @ xin[b] + b1[e] -------------
// block: 128 p x 128 o; 4 waves, each 32 p x 128 o. No LDS: direct-global frags.
__global__ __launch_bounds__(256) void k_gemm1(
    const unsigned short* __restrict__ xin, const unsigned short* __restrict__ w1b,
    const float* __restrict__ b1, const int* __restrict__ eidx,
    unsigned short* __restrict__ t1) {
  int bk = blockIdx.y; int b = bk>>1; int e = eidx[bk];
  int wave = threadIdx.x>>6, lane = threadIdx.x&63;
  int lr = lane&15, lg = lane>>4;
  int pw0 = blockIdx.x*128 + wave*32;
  const unsigned short* Xb = xin + ((size_t)b*HW + pw0)*CC;
  const unsigned short* Ae = w1b + (size_t)e*CC*CC;
  f32x4 acc[8][2];
  #pragma unroll
  for (int i=0;i<8;i++){ acc[i][0]=(f32x4){0,0,0,0}; acc[i][1]=(f32x4){0,0,0,0}; }
  #pragma unroll
  for (int k0=0;k0<CC;k0+=32){
    bf16x8 bfr0 = *(const bf16x8*)(Xb + (size_t)lr*CC      + k0 + lg*8);
    bf16x8 bfr1 = *(const bf16x8*)(Xb + (size_t)(16+lr)*CC + k0 + lg*8);
    #pragma unroll
    for (int of=0; of<8; of++){
      bf16x8 afr = *(const bf16x8*)(Ae + (size_t)(of*16+lr)*CC + k0 + lg*8);
      acc[of][0] = __builtin_amdgcn_mfma_f32_16x16x32_bf16(afr, bfr0, acc[of][0],0,0,0);
      acc[of][1] = __builtin_amdgcn_mfma_f32_16x16x32_bf16(afr, bfr1, acc[of][1],0,0,0);
    }
  }
  // C/D: p = lane&15 (+16*pf), o = of*16 + lg*4 + r  -> 4 consecutive o = 8B store
  unsigned short* T = t1 + ((size_t)bk*HW + pw0)*CC;
  #pragma unroll
  for (int of=0; of<8; of++){
    int o0 = of*16 + lg*4;
    float bs0=b1[e*CC+o0], bs1=b1[e*CC+o0+1], bs2=b1[e*CC+o0+2], bs3=b1[e*CC+o0+3];
    #pragma unroll
    for (int pf=0; pf<2; pf++){
      union { unsigned long long u; unsigned short s[4]; } pk;
      pk.s[0]=f2b(acc[of][pf][0]+bs0);
      pk.s[1]=f2b(acc[of][pf][1]+bs1);
      pk.s[2]=f2b(acc[of][pf][2]+bs2);
      pk.s[3]=f2b(acc[of][pf][3]+bs3);
      *(unsigned long long*)(T + (size_t)(pf*16+lr)*CC + o0) = pk.u;
    }
  }
}

// ---- K5: depthwise 3x3 + bias + exact GELU, [p][c] layout ----------------------
__global__ __launch_bounds__(256) void k_dw(
    const unsigned short* __restrict__ t1, const float* __restrict__ dw,
    const float* __restrict__ bdw, const int* __restrict__ eidx,
    unsigned short* __restrict__ t3) {
  int bk = blockIdx.y; int e = eidx[bk];
  int idx = blockIdx.x*256 + threadIdx.x;
  int p = idx >> 4; int cg = (idx & 15) << 3;
  int h = p >> 7, w = p & (WW-1);
  const unsigned short* base = t1 + (size_t)bk*HW*CC + cg;
  const float* kd = dw + ((size_t)e*CC + cg)*9;
  float acc[8];
  #pragma unroll
  for (int j=0;j<8;j++) acc[j] = bdw[e*CC+cg+j];
  #pragma unroll
  for (int dy=-1;dy<=1;dy++){
    int h2=h+dy; if (h2<0||h2>=HH) continue;
    #pragma unroll
    for (int dx=-1;dx<=1;dx++){
      int ww=w+dx; if (ww<0||ww>=WW) continue;
      bf16x8 v = *(const bf16x8*)(base + (size_t)(h2*WW+ww)*CC);
      int t=(dy+1)*3+(dx+1);
      #pragma unroll
      for (int j=0;j<8;j++) acc[j] += b2f((unsigned short)v[j]) * kd[j*9+t];
    }
  }
  unsigned short* dst = t3 + (size_t)bk*HW*CC + (size_t)p*CC + cg;
  union { bf16x8 v; unsigned short s[8]; } pk;
  #pragma unroll
  for (int j=0;j<8;j++){
    float g = 0.5f*acc[j]*(1.f+erff(acc[j]*0.70710678f));
    pk.s[j]=f2b(g);
  }
  *(bf16x8*)dst = pk.v;
}

// ---- K6: GEMM2 (MFMA bf16, both experts, gate pre-baked) + residual + bias -----
__global__ __launch_bounds__(256) void k_gemm2(
    const unsigned short* __restrict__ t3, const unsigned short* __restrict__ w2s,
    const float* __restrict__ bias_out, const float* __restrict__ x,
    float* __restrict__ out) {
  int b = blockIdx.y;
  int wave = threadIdx.x>>6, lane = threadIdx.x&63;
  int lr = lane&15, lg = lane>>4;
  int pw0 = blockIdx.x*128 + wave*32;
  f32x4 acc[8][2];
  #pragma unroll
  for (int i=0;i<8;i++){ acc[i][0]=(f32x4){0,0,0,0}; acc[i][1]=(f32x4){0,0,0,0}; }
  #pragma unroll
  for (int kk=0;kk<2;kk++){
    int bk = b*2+kk;
    const unsigned short* Xb = t3 + ((size_t)bk*HW + pw0)*CC;
    const unsigned short* Ae = w2s + (size_t)bk*CC*CC;
    #pragma unroll
    for (int k0=0;k0<CC;k0+=32){
      bf16x8 bfr0 = *(const bf16x8*)(Xb + (size_t)lr*CC      + k0 + lg*8);
      bf16x8 bfr1 = *(const bf16x8*)(Xb + (size_t)(16+lr)*CC + k0 + lg*8);
      #pragma unroll
      for (int of=0; of<8; of++){
        bf16x8 afr = *(const bf16x8*)(Ae + (size_t)(of*16+lr)*CC + k0 + lg*8);
        acc[of][0] = __builtin_amdgcn_mfma_f32_16x16x32_bf16(afr, bfr0, acc[of][0],0,0,0);
        acc[of][1] = __builtin_amdgcn_mfma_f32_16x16x32_bf16(afr, bfr1, acc[of][1],0,0,0);
      }
    }
  }
  const float* xb = x + (size_t)b*CC*HW;
  float* ob = out + (size_t)b*CC*HW;
  #pragma unroll
  for (int of=0; of<8; of++){
    int o0 = of*16 + lg*4;
    #pragma unroll
    for (int r=0;r<4;r++){
      float bo = bias_out[b*CC+o0+r];
      #pragma unroll
      for (int pf=0; pf<2; pf++){
        size_t idx = (size_t)(o0+r)*HW + pw0 + pf*16 + lr;
        ob[idx] = xb[idx] + acc[of][pf][r] + bo;
      }
    }
  }
}

extern "C" void kernel_launch(void* const* d_in, const int* in_sizes, int n_in,
                              void* d_out, int out_size, void* d_ws, size_t ws_size,
                              hipStream_t stream) {
  const float* x      = (const float*)d_in[0];
  const float* prompt = (const float*)d_in[1];
  const float* gamma  = (const float*)d_in[2];
  const float* beta   = (const float*)d_in[3];
  const float* rw     = (const float*)d_in[4];
  const float* rb     = (const float*)d_in[5];
  const float* w1     = (const float*)d_in[6];
  const float* b1     = (const float*)d_in[7];
  const float* dw     = (const float*)d_in[8];
  const float* bdw    = (const float*)d_in[9];
  const float* w2     = (const float*)d_in[10];
  const float* b2     = (const float*)d_in[11];
  const float* pw     = (const float*)d_in[12];
  const float* pb     = (const float*)d_in[13];
  float* out = (float*)d_out;

  char* base = (char*)d_ws;
  size_t off = 0;
  auto alloc = [&](size_t bytes)->void* {
    void* p = base + off;
    off = (off + bytes + 255) & ~(size_t)255;
    return p;
  };
  unsigned short* xin  = (unsigned short*)alloc((size_t)BB*HW*CC*2);     // 32 MiB [b][p][c]
  unsigned short* t1   = (unsigned short*)alloc((size_t)BB*2*HW*CC*2);   // 64 MiB [bk][p][o]
  unsigned short* t3   = (unsigned short*)alloc((size_t)BB*2*HW*CC*2);   // 64 MiB [bk][p][c]
  unsigned short* w1b  = (unsigned short*)alloc((size_t)EE*CC*CC*2);
  unsigned short* w2p  = (unsigned short*)alloc((size_t)EE*CC*CC*2);
  unsigned short* w2s  = (unsigned short*)alloc((size_t)BB*2*CC*CC*2);
  float* feat_sum      = (float*)alloc(BB*CC*4);
  int*   eidx          = (int*)alloc(BB*2*4);
  float* wgt           = (float*)alloc(BB*2*4);
  float* bias_out      = (float*)alloc(BB*CC*4);

  hipMemsetAsync(feat_sum, 0, BB*CC*4, stream);

  k_ln<<<dim3(HW/256, BB), 256, 0, stream>>>(x, gamma, beta, xin, feat_sum);
  k_prep<<<dim3(EE*CC), 128, 0, stream>>>(pw, w2, w1, w2p, w1b);
  k_router<<<dim3(1), 256, 0, stream>>>(feat_sum, prompt, rw, rb, b2, pw, pb,
                                        eidx, wgt, bias_out);
  k_scalew2<<<dim3(CC*CC/256, BB*2), 256, 0, stream>>>(w2p, eidx, wgt, w2s);
  k_gemm1<<<dim3(HW/128, BB*2), 256, 0, stream>>>(xin, w1b, b1, eidx, t1);
  k_dw<<<dim3(HW*16/256, BB*2), 256, 0, stream>>>(t1, dw, bdw, eidx, t3);
  k_gemm2<<<dim3(HW/128, BB), 256, 0, stream>>>(t3, w2s, bias_out, x, out);
}

// Round 6
// 435.725 us; speedup vs baseline: 2.0925x; 2.0925x over previous
//
#include <hip/hip_runtime.h>
#include <hip/hip_bf16.h>

#define BB 8
#define CC 128
#define HH 128
#define WW 128
#define HW (HH*WW)
#define EE 4
#define EPSL 1e-6f

typedef __attribute__((ext_vector_type(8))) short bf16x8;
typedef __attribute__((ext_vector_type(4))) float f32x4;

__device__ inline float b2f(unsigned short u){
  union { unsigned int i; float f; } v; v.i = ((unsigned int)u)<<16; return v.f;
}
__device__ inline unsigned short f2b(float f){
  union { float f; unsigned int i; } v; v.f = f;
  unsigned int x = v.i;
  return (unsigned short)((x + 0x7fffu + ((x>>16)&1u)) >> 16);
}

// ---- K1: LayerNorm over C per pixel; xin stored [b][p][c] bf16 (channel-contig)
__global__ __launch_bounds__(256) void k_ln(
    const float* __restrict__ x, const float* __restrict__ gamma,
    const float* __restrict__ beta, unsigned short* __restrict__ xin,
    float* __restrict__ feat_sum) {
  int b = blockIdx.y;
  int p = blockIdx.x*256 + threadIdx.x;
  const float* xb = x + (size_t)b*CC*HW + p;
  float s=0.f, s2=0.f;
  for (int c=0;c<CC;c++){ float v = xb[(size_t)c*HW]; s+=v; s2+=v*v; }
  float mu = s*(1.f/CC);
  float var = s2*(1.f/CC) - mu*mu;
  float rs = rsqrtf(var + EPSL);
  __shared__ float lfeat[CC];
  for (int c=threadIdx.x;c<CC;c+=256) lfeat[c]=0.f;
  __syncthreads();
  int lane = threadIdx.x & 63;
  unsigned short* xo = xin + ((size_t)b*HW + p)*CC;
  for (int c0=0;c0<CC;c0+=8){
    union { bf16x8 v; unsigned short s[8]; } pk;
    float vs[8];
    #pragma unroll
    for (int j=0;j<8;j++){
      float v = (xb[(size_t)(c0+j)*HW]-mu)*rs*gamma[c0+j]+beta[c0+j];
      vs[j]=v; pk.s[j]=f2b(v);
    }
    *(bf16x8*)(xo + c0) = pk.v;
    #pragma unroll
    for (int j=0;j<8;j++){
      float r = vs[j];
      for (int o=32;o>0;o>>=1) r += __shfl_down(r, o);
      if (lane==0) atomicAdd(&lfeat[c0+j], r);
    }
  }
  __syncthreads();
  for (int c=threadIdx.x;c<CC;c+=256) atomicAdd(&feat_sum[b*CC+c], lfeat[c]);
}

// ---- K2: router (1 block) ------------------------------------------------------
__global__ __launch_bounds__(256) void k_router(
    const float* __restrict__ feat_sum, const float* __restrict__ prompt,
    const float* __restrict__ rw, const float* __restrict__ rb,
    const float* __restrict__ b2, const float* __restrict__ pw,
    const float* __restrict__ pb,
    int* __restrict__ eidx, float* __restrict__ wgt, float* __restrict__ bias_out) {
  __shared__ float logits[BB][EE];
  __shared__ float gate[BB][EE];
  __shared__ float cb[BB][CC];
  int t = threadIdx.x;
  if (t < BB*EE) {
    int b = t/EE, e = t%EE;
    float acc = rb[e];
    for (int c=0;c<CC;c++) acc += (feat_sum[b*CC+c]*(1.f/HW))*rw[c*EE+e];
    for (int c=0;c<CC;c++) acc += prompt[b*CC+c]*rw[(CC+c)*EE+e];
    logits[b][e]=acc;
  }
  __syncthreads();
  if (t < BB) {
    int b=t;
    float m=-1e30f;
    for(int e=0;e<EE;e++) m=fmaxf(m,logits[b][e]);
    float s=0.f, pr[EE];
    for(int e=0;e<EE;e++){ pr[e]=__expf(logits[b][e]-m); s+=pr[e]; }
    for(int e=0;e<EE;e++){ pr[e]/=s; gate[b][e]=0.f; }
    int i1=0; for(int e=1;e<EE;e++) if (pr[e]>pr[i1]) i1=e;
    int i2=-1; for(int e=0;e<EE;e++){ if(e==i1) continue; if(i2<0||pr[e]>pr[i2]) i2=e; }
    eidx[b*2]=i1; eidx[b*2+1]=i2;
    wgt[b*2]=pr[i1]; wgt[b*2+1]=pr[i2];
    gate[b][i1]=pr[i1]; gate[b][i2]=pr[i2];
  }
  __syncthreads();
  for (int i=t;i<BB*CC;i+=256){
    int b=i/CC, c=i%CC;
    float a=0.f;
    for(int e=0;e<EE;e++) a += gate[b][e]*b2[e*CC+c];
    cb[b][c]=a;
  }
  __syncthreads();
  for (int i=t;i<BB*CC;i+=256){
    int b=i/CC, o=i%CC;
    float a=pb[o];
    for (int c=0;c<CC;c++) a += pw[o*CC+c]*cb[b][c];
    bias_out[b*CC+o]=a;
  }
}

// ---- K3: prep: w2p[e] = bf16(pw @ w2[e]); w1b[e] = bf16(w1[e]) -----------------
__global__ __launch_bounds__(128) void k_prep(
    const float* __restrict__ pw, const float* __restrict__ w2,
    const float* __restrict__ w1,
    unsigned short* __restrict__ w2p, unsigned short* __restrict__ w1b){
  int eo = blockIdx.x; int e = eo/CC, o = eo%CC;
  int c = threadIdx.x;
  float a=0.f;
  for (int m=0;m<CC;m++) a += pw[o*CC+m]*w2[((size_t)e*CC+m)*CC+c];
  w2p[((size_t)e*CC+o)*CC+c] = f2b(a);
  w1b[((size_t)e*CC+o)*CC+c] = f2b(w1[((size_t)e*CC+o)*CC+c]);
}

// ---- K3b: w2s[bk] = bf16(wgt[bk] * w2p[e[bk]]) (gate baked into weights) -------
__global__ __launch_bounds__(256) void k_scalew2(
    const unsigned short* __restrict__ w2p, const int* __restrict__ eidx,
    const float* __restrict__ wgt, unsigned short* __restrict__ w2s){
  int bk = blockIdx.y;
  int e = eidx[bk]; float wv = wgt[bk];
  int i = blockIdx.x*256 + threadIdx.x;
  const unsigned short* src = w2p + (size_t)e*CC*CC;
  w2s[(size_t)bk*CC*CC + i] = f2b(wv * b2f(src[i]));
}

// ---- K4: GEMM1 (MFMA bf16): t1[bk][p][o] = w1b[e] @ xin[b] + b1[e] -------------
// block: 128 p x 128 o; 4 waves, each 32 p x 128 o. No LDS: direct-global frags.
__global__ __launch_bounds__(256) void k_gemm1(
    const unsigned short* __restrict__ xin, const unsigned short* __restrict__ w1b,
    const float* __restrict__ b1, const int* __restrict__ eidx,
    unsigned short* __restrict__ t1) {
  int bk = blockIdx.y; int b = bk>>1; int e = eidx[bk];
  int wave = threadIdx.x>>6, lane = threadIdx.x&63;
  int lr = lane&15, lg = lane>>4;
  int pw0 = blockIdx.x*128 + wave*32;
  const unsigned short* Xb = xin + ((size_t)b*HW + pw0)*CC;
  const unsigned short* Ae = w1b + (size_t)e*CC*CC;
  f32x4 acc[8][2];
  #pragma unroll
  for (int i=0;i<8;i++){ acc[i][0]=(f32x4){0,0,0,0}; acc[i][1]=(f32x4){0,0,0,0}; }
  #pragma unroll
  for (int k0=0;k0<CC;k0+=32){
    bf16x8 bfr0 = *(const bf16x8*)(Xb + (size_t)lr*CC      + k0 + lg*8);
    bf16x8 bfr1 = *(const bf16x8*)(Xb + (size_t)(16+lr)*CC + k0 + lg*8);
    #pragma unroll
    for (int of=0; of<8; of++){
      bf16x8 afr = *(const bf16x8*)(Ae + (size_t)(of*16+lr)*CC + k0 + lg*8);
      acc[of][0] = __builtin_amdgcn_mfma_f32_16x16x32_bf16(afr, bfr0, acc[of][0],0,0,0);
      acc[of][1] = __builtin_amdgcn_mfma_f32_16x16x32_bf16(afr, bfr1, acc[of][1],0,0,0);
    }
  }
  // C/D: p = lane&15 (+16*pf), o = of*16 + lg*4 + r  -> 4 consecutive o = 8B store
  unsigned short* T = t1 + ((size_t)bk*HW + pw0)*CC;
  #pragma unroll
  for (int of=0; of<8; of++){
    int o0 = of*16 + lg*4;
    float bs0=b1[e*CC+o0], bs1=b1[e*CC+o0+1], bs2=b1[e*CC+o0+2], bs3=b1[e*CC+o0+3];
    #pragma unroll
    for (int pf=0; pf<2; pf++){
      union { unsigned long long u; unsigned short s[4]; } pk;
      pk.s[0]=f2b(acc[of][pf][0]+bs0);
      pk.s[1]=f2b(acc[of][pf][1]+bs1);
      pk.s[2]=f2b(acc[of][pf][2]+bs2);
      pk.s[3]=f2b(acc[of][pf][3]+bs3);
      *(unsigned long long*)(T + (size_t)(pf*16+lr)*CC + o0) = pk.u;
    }
  }
}

// ---- K5: depthwise 3x3 + bias + exact GELU, [p][c] layout ----------------------
// Block = one image row (128 px x 128 ch). Thread = 8 px strip x 8 ch.
// Weights staged in LDS (contiguous copy); inputs: 10 overlapping bf16x8 loads/row.
__global__ __launch_bounds__(256) void k_dw(
    const unsigned short* __restrict__ t1, const float* __restrict__ dw,
    const float* __restrict__ bdw, const int* __restrict__ eidx,
    unsigned short* __restrict__ t3) {
  int bk = blockIdx.y; int e = eidx[bk];
  int h  = blockIdx.x;
  int cg = (threadIdx.x & 15) * 8;     // channel group (8 ch)
  int ws = (threadIdx.x >> 4) * 8;     // pixel strip start (8 px)

  __shared__ float skd[CC*9];          // dw[e] contiguous: [c][tap]
  __shared__ float sbd[CC];
  {
    const float* src = dw + (size_t)e*CC*9;
    for (int i=threadIdx.x; i<CC*9; i+=256) skd[i] = src[i];
    for (int i=threadIdx.x; i<CC;   i+=256) sbd[i] = bdw[e*CC+i];
  }
  __syncthreads();

  float acc[8][8];
  #pragma unroll
  for (int px=0; px<8; px++)
    #pragma unroll
    for (int j=0; j<8; j++) acc[px][j] = sbd[cg+j];

  const unsigned short* rowbase = t1 + ((size_t)bk*HW + (size_t)h*WW)*CC + cg;

  #pragma unroll
  for (int dy=0; dy<3; dy++){
    int h2 = h + dy - 1;
    if (h2 < 0 || h2 >= HH) continue;
    const unsigned short* rp = rowbase + (size_t)(dy-1)*WW*CC;
    // 10 overlapping column vectors ws-1 .. ws+8
    bf16x8 v[10];
    #pragma unroll
    for (int t=0; t<10; t++){
      int wc = ws + t - 1;
      if (wc >= 0 && wc < WW) v[t] = *(const bf16x8*)(rp + (size_t)wc*CC);
      else                    v[t] = (bf16x8){0,0,0,0,0,0,0,0};
    }
    #pragma unroll
    for (int dx=0; dx<3; dx++){
      float wk[8];
      #pragma unroll
      for (int j=0; j<8; j++) wk[j] = skd[(cg+j)*9 + dy*3 + dx];
      #pragma unroll
      for (int px=0; px<8; px++){
        #pragma unroll
        for (int j=0; j<8; j++)
          acc[px][j] += b2f((unsigned short)v[px+dx][j]) * wk[j];
      }
    }
  }

  unsigned short* dst = t3 + ((size_t)bk*HW + (size_t)h*WW + ws)*CC + cg;
  #pragma unroll
  for (int px=0; px<8; px++){
    union { bf16x8 v; unsigned short s[8]; } pk;
    #pragma unroll
    for (int j=0; j<8; j++){
      float a = acc[px][j];
      float g = 0.5f*a*(1.f+erff(a*0.70710678f));
      pk.s[j] = f2b(g);
    }
    *(bf16x8*)(dst + (size_t)px*CC) = pk.v;
  }
}

// ---- K6: GEMM2 (MFMA bf16, both experts, gate pre-baked) + residual + bias -----
__global__ __launch_bounds__(256) void k_gemm2(
    const unsigned short* __restrict__ t3, const unsigned short* __restrict__ w2s,
    const float* __restrict__ bias_out, const float* __restrict__ x,
    float* __restrict__ out) {
  int b = blockIdx.y;
  int wave = threadIdx.x>>6, lane = threadIdx.x&63;
  int lr = lane&15, lg = lane>>4;
  int pw0 = blockIdx.x*128 + wave*32;
  f32x4 acc[8][2];
  #pragma unroll
  for (int i=0;i<8;i++){ acc[i][0]=(f32x4){0,0,0,0}; acc[i][1]=(f32x4){0,0,0,0}; }
  #pragma unroll
  for (int kk=0;kk<2;kk++){
    int bk = b*2+kk;
    const unsigned short* Xb = t3 + ((size_t)bk*HW + pw0)*CC;
    const unsigned short* Ae = w2s + (size_t)bk*CC*CC;
    #pragma unroll
    for (int k0=0;k0<CC;k0+=32){
      bf16x8 bfr0 = *(const bf16x8*)(Xb + (size_t)lr*CC      + k0 + lg*8);
      bf16x8 bfr1 = *(const bf16x8*)(Xb + (size_t)(16+lr)*CC + k0 + lg*8);
      #pragma unroll
      for (int of=0; of<8; of++){
        bf16x8 afr = *(const bf16x8*)(Ae + (size_t)(of*16+lr)*CC + k0 + lg*8);
        acc[of][0] = __builtin_amdgcn_mfma_f32_16x16x32_bf16(afr, bfr0, acc[of][0],0,0,0);
        acc[of][1] = __builtin_amdgcn_mfma_f32_16x16x32_bf16(afr, bfr1, acc[of][1],0,0,0);
      }
    }
  }
  const float* xb = x + (size_t)b*CC*HW;
  float* ob = out + (size_t)b*CC*HW;
  #pragma unroll
  for (int of=0; of<8; of++){
    int o0 = of*16 + lg*4;
    #pragma unroll
    for (int r=0;r<4;r++){
      float bo = bias_out[b*CC+o0+r];
      #pragma unroll
      for (int pf=0; pf<2; pf++){
        size_t idx = (size_t)(o0+r)*HW + pw0 + pf*16 + lr;
        ob[idx] = xb[idx] + acc[of][pf][r] + bo;
      }
    }
  }
}

extern "C" void kernel_launch(void* const* d_in, const int* in_sizes, int n_in,
                              void* d_out, int out_size, void* d_ws, size_t ws_size,
                              hipStream_t stream) {
  const float* x      = (const float*)d_in[0];
  const float* prompt = (const float*)d_in[1];
  const float* gamma  = (const float*)d_in[2];
  const float* beta   = (const float*)d_in[3];
  const float* rw     = (const float*)d_in[4];
  const float* rb     = (const float*)d_in[5];
  const float* w1     = (const float*)d_in[6];
  const float* b1     = (const float*)d_in[7];
  const float* dw     = (const float*)d_in[8];
  const float* bdw    = (const float*)d_in[9];
  const float* w2     = (const float*)d_in[10];
  const float* b2     = (const float*)d_in[11];
  const float* pw     = (const float*)d_in[12];
  const float* pb     = (const float*)d_in[13];
  float* out = (float*)d_out;

  char* base = (char*)d_ws;
  size_t off = 0;
  auto alloc = [&](size_t bytes)->void* {
    void* p = base + off;
    off = (off + bytes + 255) & ~(size_t)255;
    return p;
  };
  unsigned short* xin  = (unsigned short*)alloc((size_t)BB*HW*CC*2);     // 32 MiB [b][p][c]
  unsigned short* t1   = (unsigned short*)alloc((size_t)BB*2*HW*CC*2);   // 64 MiB [bk][p][o]
  unsigned short* t3   = (unsigned short*)alloc((size_t)BB*2*HW*CC*2);   // 64 MiB [bk][p][c]
  unsigned short* w1b  = (unsigned short*)alloc((size_t)EE*CC*CC*2);
  unsigned short* w2p  = (unsigned short*)alloc((size_t)EE*CC*CC*2);
  unsigned short* w2s  = (unsigned short*)alloc((size_t)BB*2*CC*CC*2);
  float* feat_sum      = (float*)alloc(BB*CC*4);
  int*   eidx          = (int*)alloc(BB*2*4);
  float* wgt           = (float*)alloc(BB*2*4);
  float* bias_out      = (float*)alloc(BB*CC*4);

  hipMemsetAsync(feat_sum, 0, BB*CC*4, stream);

  k_ln<<<dim3(HW/256, BB), 256, 0, stream>>>(x, gamma, beta, xin, feat_sum);
  k_prep<<<dim3(EE*CC), 128, 0, stream>>>(pw, w2, w1, w2p, w1b);
  k_router<<<dim3(1), 256, 0, stream>>>(feat_sum, prompt, rw, rb, b2, pw, pb,
                                        eidx, wgt, bias_out);
  k_scalew2<<<dim3(CC*CC/256, BB*2), 256, 0, stream>>>(w2p, eidx, wgt, w2s);
  k_gemm1<<<dim3(HW/128, BB*2), 256, 0, stream>>>(xin, w1b, b1, eidx, t1);
  k_dw<<<dim3(HH, BB*2), 256, 0, stream>>>(t1, dw, bdw, eidx, t3);
  k_gemm2<<<dim3(HW/128, BB), 256, 0, stream>>>(t3, w2s, bias_out, x, out);
}

// Round 7
// 365.874 us; speedup vs baseline: 2.4920x; 1.1909x over previous
//
#include <hip/hip_runtime.h>
#include <hip/hip_bf16.h>

#define BB 8
#define CC 128
#define HH 128
#define WW 128
#define HW (HH*WW)
#define EE 4
#define EPSL 1e-6f
#define PT1 8
#define PT2 4

typedef __attribute__((ext_vector_type(8))) short bf16x8;
typedef __attribute__((ext_vector_type(4))) float f32x4;

__device__ inline float b2f(unsigned short u){
  union { unsigned int i; float f; } v; v.i = ((unsigned int)u)<<16; return v.f;
}
__device__ inline unsigned short f2b(float f){
  union { float f; unsigned int i; } v; v.f = f;
  unsigned int x = v.i;
  return (unsigned short)((x + 0x7fffu + ((x>>16)&1u)) >> 16);
}

// ---- K1: LayerNorm over C per pixel; xin stored [b][p][c] bf16 (channel-contig)
__global__ __launch_bounds__(256) void k_ln(
    const float* __restrict__ x, const float* __restrict__ gamma,
    const float* __restrict__ beta, unsigned short* __restrict__ xin,
    float* __restrict__ feat_sum) {
  int b = blockIdx.y;
  int p = blockIdx.x*256 + threadIdx.x;
  const float* xb = x + (size_t)b*CC*HW + p;
  float s=0.f, s2=0.f;
  for (int c=0;c<CC;c++){ float v = xb[(size_t)c*HW]; s+=v; s2+=v*v; }
  float mu = s*(1.f/CC);
  float var = s2*(1.f/CC) - mu*mu;
  float rs = rsqrtf(var + EPSL);
  __shared__ float lfeat[CC];
  for (int c=threadIdx.x;c<CC;c+=256) lfeat[c]=0.f;
  __syncthreads();
  int lane = threadIdx.x & 63;
  unsigned short* xo = xin + ((size_t)b*HW + p)*CC;
  for (int c0=0;c0<CC;c0+=8){
    union { bf16x8 v; unsigned short s[8]; } pk;
    float vs[8];
    #pragma unroll
    for (int j=0;j<8;j++){
      float v = (xb[(size_t)(c0+j)*HW]-mu)*rs*gamma[c0+j]+beta[c0+j];
      vs[j]=v; pk.s[j]=f2b(v);
    }
    *(bf16x8*)(xo + c0) = pk.v;
    #pragma unroll
    for (int j=0;j<8;j++){
      float r = vs[j];
      for (int o=32;o>0;o>>=1) r += __shfl_down(r, o);
      if (lane==0) atomicAdd(&lfeat[c0+j], r);
    }
  }
  __syncthreads();
  for (int c=threadIdx.x;c<CC;c+=256) atomicAdd(&feat_sum[b*CC+c], lfeat[c]);
}

// ---- K2: router (1 block) ------------------------------------------------------
__global__ __launch_bounds__(256) void k_router(
    const float* __restrict__ feat_sum, const float* __restrict__ prompt,
    const float* __restrict__ rw, const float* __restrict__ rb,
    const float* __restrict__ b2, const float* __restrict__ pw,
    const float* __restrict__ pb,
    int* __restrict__ eidx, float* __restrict__ wgt, float* __restrict__ bias_out) {
  __shared__ float logits[BB][EE];
  __shared__ float gate[BB][EE];
  __shared__ float cb[BB][CC];
  int t = threadIdx.x;
  if (t < BB*EE) {
    int b = t/EE, e = t%EE;
    float acc = rb[e];
    for (int c=0;c<CC;c++) acc += (feat_sum[b*CC+c]*(1.f/HW))*rw[c*EE+e];
    for (int c=0;c<CC;c++) acc += prompt[b*CC+c]*rw[(CC+c)*EE+e];
    logits[b][e]=acc;
  }
  __syncthreads();
  if (t < BB) {
    int b=t;
    float m=-1e30f;
    for(int e=0;e<EE;e++) m=fmaxf(m,logits[b][e]);
    float s=0.f, pr[EE];
    for(int e=0;e<EE;e++){ pr[e]=__expf(logits[b][e]-m); s+=pr[e]; }
    for(int e=0;e<EE;e++){ pr[e]/=s; gate[b][e]=0.f; }
    int i1=0; for(int e=1;e<EE;e++) if (pr[e]>pr[i1]) i1=e;
    int i2=-1; for(int e=0;e<EE;e++){ if(e==i1) continue; if(i2<0||pr[e]>pr[i2]) i2=e; }
    eidx[b*2]=i1; eidx[b*2+1]=i2;
    wgt[b*2]=pr[i1]; wgt[b*2+1]=pr[i2];
    gate[b][i1]=pr[i1]; gate[b][i2]=pr[i2];
  }
  __syncthreads();
  for (int i=t;i<BB*CC;i+=256){
    int b=i/CC, c=i%CC;
    float a=0.f;
    for(int e=0;e<EE;e++) a += gate[b][e]*b2[e*CC+c];
    cb[b][c]=a;
  }
  __syncthreads();
  for (int i=t;i<BB*CC;i+=256){
    int b=i/CC, o=i%CC;
    float a=pb[o];
    for (int c=0;c<CC;c++) a += pw[o*CC+c]*cb[b][c];
    bias_out[b*CC+o]=a;
  }
}

// ---- K3: prep: w2p[e] = bf16(pw @ w2[e]); w1b[e] = bf16(w1[e]) -----------------
__global__ __launch_bounds__(128) void k_prep(
    const float* __restrict__ pw, const float* __restrict__ w2,
    const float* __restrict__ w1,
    unsigned short* __restrict__ w2p, unsigned short* __restrict__ w1b){
  int eo = blockIdx.x; int e = eo/CC, o = eo%CC;
  int c = threadIdx.x;
  float a=0.f;
  for (int m=0;m<CC;m++) a += pw[o*CC+m]*w2[((size_t)e*CC+m)*CC+c];
  w2p[((size_t)e*CC+o)*CC+c] = f2b(a);
  w1b[((size_t)e*CC+o)*CC+c] = f2b(w1[((size_t)e*CC+o)*CC+c]);
}

// ---- K3b: w2s[bk] = bf16(wgt[bk] * w2p[e[bk]]) (gate baked into weights) -------
__global__ __launch_bounds__(256) void k_scalew2(
    const unsigned short* __restrict__ w2p, const int* __restrict__ eidx,
    const float* __restrict__ wgt, unsigned short* __restrict__ w2s){
  int bk = blockIdx.y;
  int e = eidx[bk]; float wv = wgt[bk];
  int i = blockIdx.x*256 + threadIdx.x;
  const unsigned short* src = w2p + (size_t)e*CC*CC;
  w2s[(size_t)bk*CC*CC + i] = f2b(wv * b2f(src[i]));
}

// ---- K4: GEMM1 (MFMA bf16): t1[bk][p][o] = w1b[e] @ xin[b] + b1[e] -------------
// 4 waves; wave owns 32-o x 128-k A slice in regs. PT1 pixel tiles of 32 px,
// B fragments double-buffered (prefetch 1 tile ahead). All indices static.
__global__ __launch_bounds__(256) void k_gemm1(
    const unsigned short* __restrict__ xin, const unsigned short* __restrict__ w1b,
    const float* __restrict__ b1, const int* __restrict__ eidx,
    unsigned short* __restrict__ t1) {
  int bk = blockIdx.y; int b = bk>>1; int e = eidx[bk];
  int wave = threadIdx.x>>6, lane = threadIdx.x&63;
  int lr = lane&15, lg = lane>>4;
  int ob = wave*32;
  const unsigned short* Ae = w1b + (size_t)e*CC*CC;
  bf16x8 A[2][4];
  #pragma unroll
  for (int of=0; of<2; of++)
    #pragma unroll
    for (int k0=0; k0<4; k0++)
      A[of][k0] = *(const bf16x8*)(Ae + (size_t)(ob+of*16+lr)*CC + k0*32 + lg*8);
  float bs[2][4];
  #pragma unroll
  for (int of=0; of<2; of++)
    #pragma unroll
    for (int r=0; r<4; r++)
      bs[of][r] = b1[e*CC + ob + of*16 + lg*4 + r];

  int p_start = blockIdx.x * (32*PT1);
  const unsigned short* Xb = xin + ((size_t)b*HW + p_start)*CC;
  unsigned short* T = t1 + ((size_t)bk*HW + p_start)*CC;

  bf16x8 Ba[2][4], Bb[2][4];
  auto loadB = [&](bf16x8 (&Bf)[2][4], int tt){
    const unsigned short* Xt = Xb + (size_t)tt*32*CC;
    #pragma unroll
    for (int pf=0; pf<2; pf++)
      #pragma unroll
      for (int k0=0; k0<4; k0++)
        Bf[pf][k0] = *(const bf16x8*)(Xt + (size_t)(pf*16+lr)*CC + k0*32 + lg*8);
  };
  auto comp = [&](bf16x8 (&Bf)[2][4], int tt){
    f32x4 acc[2][2];
    #pragma unroll
    for (int of=0; of<2; of++){ acc[of][0]=(f32x4){0,0,0,0}; acc[of][1]=(f32x4){0,0,0,0}; }
    #pragma unroll
    for (int k0=0; k0<4; k0++)
      #pragma unroll
      for (int of=0; of<2; of++)
        #pragma unroll
        for (int pf=0; pf<2; pf++)
          acc[of][pf] = __builtin_amdgcn_mfma_f32_16x16x32_bf16(A[of][k0], Bf[pf][k0], acc[of][pf],0,0,0);
    unsigned short* Tt = T + (size_t)tt*32*CC;
    #pragma unroll
    for (int of=0; of<2; of++){
      int o0 = ob + of*16 + lg*4;
      #pragma unroll
      for (int pf=0; pf<2; pf++){
        union { unsigned long long u; unsigned short s[4]; } pk;
        #pragma unroll
        for (int r=0; r<4; r++) pk.s[r]=f2b(acc[of][pf][r]+bs[of][r]);
        *(unsigned long long*)(Tt + (size_t)(pf*16+lr)*CC + o0) = pk.u;
      }
    }
  };

  loadB(Ba, 0);
  #pragma unroll
  for (int t=0; t<PT1; t++){
    if ((t&1)==0){ if (t+1<PT1) loadB(Bb, t+1); comp(Ba, t); }
    else         { if (t+1<PT1) loadB(Ba, t+1); comp(Bb, t); }
  }
}

// ---- K5: depthwise 3x3 + bias + exact GELU, [p][c] layout ----------------------
__global__ __launch_bounds__(256) void k_dw(
    const unsigned short* __restrict__ t1, const float* __restrict__ dw,
    const float* __restrict__ bdw, const int* __restrict__ eidx,
    unsigned short* __restrict__ t3) {
  int bk = blockIdx.y; int e = eidx[bk];
  int h  = blockIdx.x;
  int cg = (threadIdx.x & 15) * 8;
  int ws = (threadIdx.x >> 4) * 8;

  __shared__ float skd[CC*9];
  __shared__ float sbd[CC];
  {
    const float* src = dw + (size_t)e*CC*9;
    for (int i=threadIdx.x; i<CC*9; i+=256) skd[i] = src[i];
    for (int i=threadIdx.x; i<CC;   i+=256) sbd[i] = bdw[e*CC+i];
  }
  __syncthreads();

  float acc[8][8];
  #pragma unroll
  for (int px=0; px<8; px++)
    #pragma unroll
    for (int j=0; j<8; j++) acc[px][j] = sbd[cg+j];

  const unsigned short* rowbase = t1 + ((size_t)bk*HW + (size_t)h*WW)*CC + cg;

  #pragma unroll
  for (int dy=0; dy<3; dy++){
    int h2 = h + dy - 1;
    if (h2 < 0 || h2 >= HH) continue;
    const unsigned short* rp = rowbase + (size_t)(dy-1)*WW*CC;
    bf16x8 v[10];
    #pragma unroll
    for (int t=0; t<10; t++){
      int wc = ws + t - 1;
      if (wc >= 0 && wc < WW) v[t] = *(const bf16x8*)(rp + (size_t)wc*CC);
      else                    v[t] = (bf16x8){0,0,0,0,0,0,0,0};
    }
    #pragma unroll
    for (int dx=0; dx<3; dx++){
      float wk[8];
      #pragma unroll
      for (int j=0; j<8; j++) wk[j] = skd[(cg+j)*9 + dy*3 + dx];
      #pragma unroll
      for (int px=0; px<8; px++){
        #pragma unroll
        for (int j=0; j<8; j++)
          acc[px][j] += b2f((unsigned short)v[px+dx][j]) * wk[j];
      }
    }
  }

  unsigned short* dst = t3 + ((size_t)bk*HW + (size_t)h*WW + ws)*CC + cg;
  #pragma unroll
  for (int px=0; px<8; px++){
    union { bf16x8 v; unsigned short s[8]; } pk;
    #pragma unroll
    for (int j=0; j<8; j++){
      float a = acc[px][j];
      float g = 0.5f*a*(1.f+erff(a*0.70710678f));
      pk.s[j] = f2b(g);
    }
    *(bf16x8*)(dst + (size_t)px*CC) = pk.v;
  }
}

// ---- K6: GEMM2 (MFMA bf16, both experts in regs, gate pre-baked) + residual ----
__global__ __launch_bounds__(256) void k_gemm2(
    const unsigned short* __restrict__ t3, const unsigned short* __restrict__ w2s,
    const float* __restrict__ bias_out, const float* __restrict__ x,
    float* __restrict__ out) {
  int b = blockIdx.y;
  int wave = threadIdx.x>>6, lane = threadIdx.x&63;
  int lr = lane&15, lg = lane>>4;
  int ob = wave*32;
  bf16x8 A[2][2][4];
  #pragma unroll
  for (int kk=0; kk<2; kk++){
    const unsigned short* Ae = w2s + (size_t)(b*2+kk)*CC*CC;
    #pragma unroll
    for (int of=0; of<2; of++)
      #pragma unroll
      for (int k0=0; k0<4; k0++)
        A[kk][of][k0] = *(const bf16x8*)(Ae + (size_t)(ob+of*16+lr)*CC + k0*32 + lg*8);
  }
  float bo[2][4];
  #pragma unroll
  for (int of=0; of<2; of++)
    #pragma unroll
    for (int r=0; r<4; r++)
      bo[of][r] = bias_out[b*CC + ob + of*16 + lg*4 + r];

  int p_start = blockIdx.x * (32*PT2);
  const unsigned short* X0 = t3 + ((size_t)(b*2+0)*HW + p_start)*CC;
  const unsigned short* X1 = t3 + ((size_t)(b*2+1)*HW + p_start)*CC;
  const float* xb = x + (size_t)b*CC*HW;
  float* obp = out + (size_t)b*CC*HW;

  bf16x8 Ba[2][4], Bb[2][4];
  auto loadB = [&](bf16x8 (&Bf)[2][4], int g){   // g = tile*2 + kk
    const unsigned short* Xt = ((g&1) ? X1 : X0) + (size_t)(g>>1)*32*CC;
    #pragma unroll
    for (int pf=0; pf<2; pf++)
      #pragma unroll
      for (int k0=0; k0<4; k0++)
        Bf[pf][k0] = *(const bf16x8*)(Xt + (size_t)(pf*16+lr)*CC + k0*32 + lg*8);
  };

  f32x4 acc[2][2];
  auto comp = [&](bf16x8 (&Bf)[2][4], int g){
    int kk = g&1, tt = g>>1;
    if (kk==0){
      #pragma unroll
      for (int of=0; of<2; of++){ acc[of][0]=(f32x4){0,0,0,0}; acc[of][1]=(f32x4){0,0,0,0}; }
    }
    #pragma unroll
    for (int k0=0; k0<4; k0++)
      #pragma unroll
      for (int of=0; of<2; of++)
        #pragma unroll
        for (int pf=0; pf<2; pf++)
          acc[of][pf] = (kk==0)
            ? __builtin_amdgcn_mfma_f32_16x16x32_bf16(A[0][of][k0], Bf[pf][k0], acc[of][pf],0,0,0)
            : __builtin_amdgcn_mfma_f32_16x16x32_bf16(A[1][of][k0], Bf[pf][k0], acc[of][pf],0,0,0);
    if (kk==1){
      #pragma unroll
      for (int of=0; of<2; of++){
        int o0 = ob + of*16 + lg*4;
        #pragma unroll
        for (int r=0; r<4; r++){
          #pragma unroll
          for (int pf=0; pf<2; pf++){
            size_t idx = (size_t)(o0+r)*HW + p_start + tt*32 + pf*16 + lr;
            obp[idx] = xb[idx] + acc[of][pf][r] + bo[of][r];
          }
        }
      }
    }
  };

  loadB(Ba, 0);
  #pragma unroll
  for (int g=0; g<2*PT2; g++){
    if ((g&1)==0){ if (g+1<2*PT2) loadB(Bb, g+1); comp(Ba, g); }
    else         { if (g+1<2*PT2) loadB(Ba, g+1); comp(Bb, g); }
  }
}

extern "C" void kernel_launch(void* const* d_in, const int* in_sizes, int n_in,
                              void* d_out, int out_size, void* d_ws, size_t ws_size,
                              hipStream_t stream) {
  const float* x      = (const float*)d_in[0];
  const float* prompt = (const float*)d_in[1];
  const float* gamma  = (const float*)d_in[2];
  const float* beta   = (const float*)d_in[3];
  const float* rw     = (const float*)d_in[4];
  const float* rb     = (const float*)d_in[5];
  const float* w1     = (const float*)d_in[6];
  const float* b1     = (const float*)d_in[7];
  const float* dw     = (const float*)d_in[8];
  const float* bdw    = (const float*)d_in[9];
  const float* w2     = (const float*)d_in[10];
  const float* b2     = (const float*)d_in[11];
  const float* pw     = (const float*)d_in[12];
  const float* pb     = (const float*)d_in[13];
  float* out = (float*)d_out;

  char* base = (char*)d_ws;
  size_t off = 0;
  auto alloc = [&](size_t bytes)->void* {
    void* p = base + off;
    off = (off + bytes + 255) & ~(size_t)255;
    return p;
  };
  unsigned short* xin  = (unsigned short*)alloc((size_t)BB*HW*CC*2);     // 32 MiB [b][p][c]
  unsigned short* t1   = (unsigned short*)alloc((size_t)BB*2*HW*CC*2);   // 64 MiB [bk][p][o]
  unsigned short* t3   = (unsigned short*)alloc((size_t)BB*2*HW*CC*2);   // 64 MiB [bk][p][c]
  unsigned short* w1b  = (unsigned short*)alloc((size_t)EE*CC*CC*2);
  unsigned short* w2p  = (unsigned short*)alloc((size_t)EE*CC*CC*2);
  unsigned short* w2s  = (unsigned short*)alloc((size_t)BB*2*CC*CC*2);
  float* feat_sum      = (float*)alloc(BB*CC*4);
  int*   eidx          = (int*)alloc(BB*2*4);
  float* wgt           = (float*)alloc(BB*2*4);
  float* bias_out      = (float*)alloc(BB*CC*4);

  hipMemsetAsync(feat_sum, 0, BB*CC*4, stream);

  k_ln<<<dim3(HW/256, BB), 256, 0, stream>>>(x, gamma, beta, xin, feat_sum);
  k_prep<<<dim3(EE*CC), 128, 0, stream>>>(pw, w2, w1, w2p, w1b);
  k_router<<<dim3(1), 256, 0, stream>>>(feat_sum, prompt, rw, rb, b2, pw, pb,
                                        eidx, wgt, bias_out);
  k_scalew2<<<dim3(CC*CC/256, BB*2), 256, 0, stream>>>(w2p, eidx, wgt, w2s);
  k_gemm1<<<dim3(HW/(32*PT1), BB*2), 256, 0, stream>>>(xin, w1b, b1, eidx, t1);
  k_dw<<<dim3(HH, BB*2), 256, 0, stream>>>(t1, dw, bdw, eidx, t3);
  k_gemm2<<<dim3(HW/(32*PT2), BB), 256, 0, stream>>>(t3, w2s, bias_out, x, out);
}

// Round 8
// 358.567 us; speedup vs baseline: 2.5428x; 1.0204x over previous
//
#include <hip/hip_runtime.h>
#include <hip/hip_bf16.h>

#define BB 8
#define CC 128
#define HH 128
#define WW 128
#define HW (HH*WW)
#define EE 4
#define EPSL 1e-6f
#define PT1 8
#define PT2 4
#define LNP 128

typedef __attribute__((ext_vector_type(8))) short bf16x8;
typedef __attribute__((ext_vector_type(4))) float f32x4;

__device__ inline float b2f(unsigned short u){
  union { unsigned int i; float f; } v; v.i = ((unsigned int)u)<<16; return v.f;
}
__device__ inline unsigned short f2b(float f){
  union { float f; unsigned int i; } v; v.f = f;
  unsigned int x = v.i;
  return (unsigned short)((x + 0x7fffu + ((x>>16)&1u)) >> 16);
}

// ---- K1: LayerNorm over C per pixel; xin [b][p][c] bf16, coalesced via LDS tile
__global__ __launch_bounds__(128) void k_ln(
    const float* __restrict__ x, const float* __restrict__ gamma,
    const float* __restrict__ beta, unsigned short* __restrict__ xin,
    float* __restrict__ feat_sum) {
  int b = blockIdx.y;
  int p0 = blockIdx.x*LNP;
  int tid = threadIdx.x;
  const float* xb = x + (size_t)b*CC*HW + p0 + tid;
  float s=0.f, s2=0.f;
  for (int c=0;c<CC;c++){ float v = xb[(size_t)c*HW]; s+=v; s2+=v*v; }
  float mu = s*(1.f/CC);
  float var = s2*(1.f/CC) - mu*mu;
  float rs = rsqrtf(var + EPSL);

  __shared__ unsigned short tile[LNP][CC+8];   // +8 shorts (16B) pad
  __shared__ float lfeat[CC];
  for (int c=tid;c<CC;c+=LNP) lfeat[c]=0.f;
  __syncthreads();

  int lane = tid & 63;
  for (int c0=0;c0<CC;c0+=8){
    union { bf16x8 v; unsigned short s[8]; } pk;
    float vs[8];
    #pragma unroll
    for (int j=0;j<8;j++){
      float v = (xb[(size_t)(c0+j)*HW]-mu)*rs*gamma[c0+j]+beta[c0+j];
      vs[j]=v; pk.s[j]=f2b(v);
    }
    *(bf16x8*)&tile[tid][c0] = pk.v;
    #pragma unroll
    for (int j=0;j<8;j++){
      float r = vs[j];
      for (int o=32;o>0;o>>=1) r += __shfl_down(r, o);
      if (lane==0) atomicAdd(&lfeat[c0+j], r);
    }
  }
  __syncthreads();

  // coalesced writeout: LNP rows x 256B, thread i handles 16B chunk i
  unsigned short* xo = xin + ((size_t)b*HW + p0)*CC;
  #pragma unroll
  for (int it=0; it<LNP*CC/(LNP*8); ++it){   // 16 iters
    int i = it*LNP + tid;
    int pr = i>>4, ck = (i&15)*8;
    *(bf16x8*)(xo + (size_t)i*8) = *(bf16x8*)&tile[pr][ck];
  }
  for (int c=tid;c<CC;c+=LNP) atomicAdd(&feat_sum[b*CC+c], lfeat[c]);
}

// ---- K2: router (1 block) ------------------------------------------------------
__global__ __launch_bounds__(256) void k_router(
    const float* __restrict__ feat_sum, const float* __restrict__ prompt,
    const float* __restrict__ rw, const float* __restrict__ rb,
    const float* __restrict__ b2, const float* __restrict__ pw,
    const float* __restrict__ pb,
    int* __restrict__ eidx, float* __restrict__ wgt, float* __restrict__ bias_out) {
  __shared__ float logits[BB][EE];
  __shared__ float gate[BB][EE];
  __shared__ float cb[BB][CC];
  int t = threadIdx.x;
  if (t < BB*EE) {
    int b = t/EE, e = t%EE;
    float acc = rb[e];
    for (int c=0;c<CC;c++) acc += (feat_sum[b*CC+c]*(1.f/HW))*rw[c*EE+e];
    for (int c=0;c<CC;c++) acc += prompt[b*CC+c]*rw[(CC+c)*EE+e];
    logits[b][e]=acc;
  }
  __syncthreads();
  if (t < BB) {
    int b=t;
    float m=-1e30f;
    for(int e=0;e<EE;e++) m=fmaxf(m,logits[b][e]);
    float s=0.f, pr[EE];
    for(int e=0;e<EE;e++){ pr[e]=__expf(logits[b][e]-m); s+=pr[e]; }
    for(int e=0;e<EE;e++){ pr[e]/=s; gate[b][e]=0.f; }
    int i1=0; for(int e=1;e<EE;e++) if (pr[e]>pr[i1]) i1=e;
    int i2=-1; for(int e=0;e<EE;e++){ if(e==i1) continue; if(i2<0||pr[e]>pr[i2]) i2=e; }
    eidx[b*2]=i1; eidx[b*2+1]=i2;
    wgt[b*2]=pr[i1]; wgt[b*2+1]=pr[i2];
    gate[b][i1]=pr[i1]; gate[b][i2]=pr[i2];
  }
  __syncthreads();
  for (int i=t;i<BB*CC;i+=256){
    int b=i/CC, c=i%CC;
    float a=0.f;
    for(int e=0;e<EE;e++) a += gate[b][e]*b2[e*CC+c];
    cb[b][c]=a;
  }
  __syncthreads();
  for (int i=t;i<BB*CC;i+=256){
    int b=i/CC, o=i%CC;
    float a=pb[o];
    for (int c=0;c<CC;c++) a += pw[o*CC+c]*cb[b][c];
    bias_out[b*CC+o]=a;
  }
}

// ---- K3: prep: w2p[e] = bf16(pw @ w2[e]); w1b[e] = bf16(w1[e]) -----------------
__global__ __launch_bounds__(128) void k_prep(
    const float* __restrict__ pw, const float* __restrict__ w2,
    const float* __restrict__ w1,
    unsigned short* __restrict__ w2p, unsigned short* __restrict__ w1b){
  int eo = blockIdx.x; int e = eo/CC, o = eo%CC;
  int c = threadIdx.x;
  float a=0.f;
  for (int m=0;m<CC;m++) a += pw[o*CC+m]*w2[((size_t)e*CC+m)*CC+c];
  w2p[((size_t)e*CC+o)*CC+c] = f2b(a);
  w1b[((size_t)e*CC+o)*CC+c] = f2b(w1[((size_t)e*CC+o)*CC+c]);
}

// ---- K3b: w2s[bk] = bf16(wgt[bk] * w2p[e[bk]]) (gate baked into weights) -------
__global__ __launch_bounds__(256) void k_scalew2(
    const unsigned short* __restrict__ w2p, const int* __restrict__ eidx,
    const float* __restrict__ wgt, unsigned short* __restrict__ w2s){
  int bk = blockIdx.y;
  int e = eidx[bk]; float wv = wgt[bk];
  int i = blockIdx.x*256 + threadIdx.x;
  const unsigned short* src = w2p + (size_t)e*CC*CC;
  w2s[(size_t)bk*CC*CC + i] = f2b(wv * b2f(src[i]));
}

// ---- K4: GEMM1 (MFMA bf16): t1[bk][p][o] = w1b[e] @ xin[b] + b1[e] -------------
__global__ __launch_bounds__(256) void k_gemm1(
    const unsigned short* __restrict__ xin, const unsigned short* __restrict__ w1b,
    const float* __restrict__ b1, const int* __restrict__ eidx,
    unsigned short* __restrict__ t1) {
  int bk = blockIdx.y; int b = bk>>1; int e = eidx[bk];
  int wave = threadIdx.x>>6, lane = threadIdx.x&63;
  int lr = lane&15, lg = lane>>4;
  int ob = wave*32;
  const unsigned short* Ae = w1b + (size_t)e*CC*CC;
  bf16x8 A[2][4];
  #pragma unroll
  for (int of=0; of<2; of++)
    #pragma unroll
    for (int k0=0; k0<4; k0++)
      A[of][k0] = *(const bf16x8*)(Ae + (size_t)(ob+of*16+lr)*CC + k0*32 + lg*8);
  float bs[2][4];
  #pragma unroll
  for (int of=0; of<2; of++)
    #pragma unroll
    for (int r=0; r<4; r++)
      bs[of][r] = b1[e*CC + ob + of*16 + lg*4 + r];

  int p_start = blockIdx.x * (32*PT1);
  const unsigned short* Xb = xin + ((size_t)b*HW + p_start)*CC;
  unsigned short* T = t1 + ((size_t)bk*HW + p_start)*CC;

  bf16x8 Ba[2][4], Bb[2][4];
  auto loadB = [&](bf16x8 (&Bf)[2][4], int tt){
    const unsigned short* Xt = Xb + (size_t)tt*32*CC;
    #pragma unroll
    for (int pf=0; pf<2; pf++)
      #pragma unroll
      for (int k0=0; k0<4; k0++)
        Bf[pf][k0] = *(const bf16x8*)(Xt + (size_t)(pf*16+lr)*CC + k0*32 + lg*8);
  };
  auto comp = [&](bf16x8 (&Bf)[2][4], int tt){
    f32x4 acc[2][2];
    #pragma unroll
    for (int of=0; of<2; of++){ acc[of][0]=(f32x4){0,0,0,0}; acc[of][1]=(f32x4){0,0,0,0}; }
    #pragma unroll
    for (int k0=0; k0<4; k0++)
      #pragma unroll
      for (int of=0; of<2; of++)
        #pragma unroll
        for (int pf=0; pf<2; pf++)
          acc[of][pf] = __builtin_amdgcn_mfma_f32_16x16x32_bf16(A[of][k0], Bf[pf][k0], acc[of][pf],0,0,0);
    unsigned short* Tt = T + (size_t)tt*32*CC;
    #pragma unroll
    for (int of=0; of<2; of++){
      int o0 = ob + of*16 + lg*4;
      #pragma unroll
      for (int pf=0; pf<2; pf++){
        union { unsigned long long u; unsigned short s[4]; } pk;
        #pragma unroll
        for (int r=0; r<4; r++) pk.s[r]=f2b(acc[of][pf][r]+bs[of][r]);
        *(unsigned long long*)(Tt + (size_t)(pf*16+lr)*CC + o0) = pk.u;
      }
    }
  };

  loadB(Ba, 0);
  #pragma unroll
  for (int t=0; t<PT1; t++){
    if ((t&1)==0){ if (t+1<PT1) loadB(Bb, t+1); comp(Ba, t); }
    else         { if (t+1<PT1) loadB(Ba, t+1); comp(Bb, t); }
  }
}

// ---- K5: depthwise 3x3 + bias + exact GELU, [p][c] layout ----------------------
__global__ __launch_bounds__(256) void k_dw(
    const unsigned short* __restrict__ t1, const float* __restrict__ dw,
    const float* __restrict__ bdw, const int* __restrict__ eidx,
    unsigned short* __restrict__ t3) {
  int bk = blockIdx.y; int e = eidx[bk];
  int h  = blockIdx.x;
  int cg = (threadIdx.x & 15) * 8;
  int ws = (threadIdx.x >> 4) * 8;

  __shared__ float skd[CC*9];
  __shared__ float sbd[CC];
  {
    const float* src = dw + (size_t)e*CC*9;
    for (int i=threadIdx.x; i<CC*9; i+=256) skd[i] = src[i];
    for (int i=threadIdx.x; i<CC;   i+=256) sbd[i] = bdw[e*CC+i];
  }
  __syncthreads();

  float acc[8][8];
  #pragma unroll
  for (int px=0; px<8; px++)
    #pragma unroll
    for (int j=0; j<8; j++) acc[px][j] = sbd[cg+j];

  const unsigned short* rowbase = t1 + ((size_t)bk*HW + (size_t)h*WW)*CC + cg;

  #pragma unroll
  for (int dy=0; dy<3; dy++){
    int h2 = h + dy - 1;
    if (h2 < 0 || h2 >= HH) continue;
    const unsigned short* rp = rowbase + (size_t)(dy-1)*WW*CC;
    bf16x8 v[10];
    #pragma unroll
    for (int t=0; t<10; t++){
      int wc = ws + t - 1;
      if (wc >= 0 && wc < WW) v[t] = *(const bf16x8*)(rp + (size_t)wc*CC);
      else                    v[t] = (bf16x8){0,0,0,0,0,0,0,0};
    }
    #pragma unroll
    for (int dx=0; dx<3; dx++){
      float wk[8];
      #pragma unroll
      for (int j=0; j<8; j++) wk[j] = skd[(cg+j)*9 + dy*3 + dx];
      #pragma unroll
      for (int px=0; px<8; px++){
        #pragma unroll
        for (int j=0; j<8; j++)
          acc[px][j] += b2f((unsigned short)v[px+dx][j]) * wk[j];
      }
    }
  }

  unsigned short* dst = t3 + ((size_t)bk*HW + (size_t)h*WW + ws)*CC + cg;
  #pragma unroll
  for (int px=0; px<8; px++){
    union { bf16x8 v; unsigned short s[8]; } pk;
    #pragma unroll
    for (int j=0; j<8; j++){
      float a = acc[px][j];
      float g = 0.5f*a*(1.f+erff(a*0.70710678f));
      pk.s[j] = f2b(g);
    }
    *(bf16x8*)(dst + (size_t)px*CC) = pk.v;
  }
}

// ---- K6: GEMM2 (MFMA bf16, both experts in regs, gate pre-baked) + residual ----
__global__ __launch_bounds__(256) void k_gemm2(
    const unsigned short* __restrict__ t3, const unsigned short* __restrict__ w2s,
    const float* __restrict__ bias_out, const float* __restrict__ x,
    float* __restrict__ out) {
  int b = blockIdx.y;
  int wave = threadIdx.x>>6, lane = threadIdx.x&63;
  int lr = lane&15, lg = lane>>4;
  int ob = wave*32;
  bf16x8 A[2][2][4];
  #pragma unroll
  for (int kk=0; kk<2; kk++){
    const unsigned short* Ae = w2s + (size_t)(b*2+kk)*CC*CC;
    #pragma unroll
    for (int of=0; of<2; of++)
      #pragma unroll
      for (int k0=0; k0<4; k0++)
        A[kk][of][k0] = *(const bf16x8*)(Ae + (size_t)(ob+of*16+lr)*CC + k0*32 + lg*8);
  }
  float bo[2][4];
  #pragma unroll
  for (int of=0; of<2; of++)
    #pragma unroll
    for (int r=0; r<4; r++)
      bo[of][r] = bias_out[b*CC + ob + of*16 + lg*4 + r];

  int p_start = blockIdx.x * (32*PT2);
  const unsigned short* X0 = t3 + ((size_t)(b*2+0)*HW + p_start)*CC;
  const unsigned short* X1 = t3 + ((size_t)(b*2+1)*HW + p_start)*CC;
  const float* xb = x + (size_t)b*CC*HW;
  float* obp = out + (size_t)b*CC*HW;

  bf16x8 Ba[2][4], Bb[2][4];
  auto loadB = [&](bf16x8 (&Bf)[2][4], int g){   // g = tile*2 + kk
    const unsigned short* Xt = ((g&1) ? X1 : X0) + (size_t)(g>>1)*32*CC;
    #pragma unroll
    for (int pf=0; pf<2; pf++)
      #pragma unroll
      for (int k0=0; k0<4; k0++)
        Bf[pf][k0] = *(const bf16x8*)(Xt + (size_t)(pf*16+lr)*CC + k0*32 + lg*8);
  };

  f32x4 acc[2][2];
  auto comp = [&](bf16x8 (&Bf)[2][4], int g){
    int kk = g&1, tt = g>>1;
    if (kk==0){
      #pragma unroll
      for (int of=0; of<2; of++){ acc[of][0]=(f32x4){0,0,0,0}; acc[of][1]=(f32x4){0,0,0,0}; }
    }
    #pragma unroll
    for (int k0=0; k0<4; k0++)
      #pragma unroll
      for (int of=0; of<2; of++)
        #pragma unroll
        for (int pf=0; pf<2; pf++)
          acc[of][pf] = (kk==0)
            ? __builtin_amdgcn_mfma_f32_16x16x32_bf16(A[0][of][k0], Bf[pf][k0], acc[of][pf],0,0,0)
            : __builtin_amdgcn_mfma_f32_16x16x32_bf16(A[1][of][k0], Bf[pf][k0], acc[of][pf],0,0,0);
    if (kk==1){
      #pragma unroll
      for (int of=0; of<2; of++){
        int o0 = ob + of*16 + lg*4;
        #pragma unroll
        for (int r=0; r<4; r++){
          #pragma unroll
          for (int pf=0; pf<2; pf++){
            size_t idx = (size_t)(o0+r)*HW + p_start + tt*32 + pf*16 + lr;
            obp[idx] = xb[idx] + acc[of][pf][r] + bo[of][r];
          }
        }
      }
    }
  };

  loadB(Ba, 0);
  #pragma unroll
  for (int g=0; g<2*PT2; g++){
    if ((g&1)==0){ if (g+1<2*PT2) loadB(Bb, g+1); comp(Ba, g); }
    else         { if (g+1<2*PT2) loadB(Ba, g+1); comp(Bb, g); }
  }
}

extern "C" void kernel_launch(void* const* d_in, const int* in_sizes, int n_in,
                              void* d_out, int out_size, void* d_ws, size_t ws_size,
                              hipStream_t stream) {
  const float* x      = (const float*)d_in[0];
  const float* prompt = (const float*)d_in[1];
  const float* gamma  = (const float*)d_in[2];
  const float* beta   = (const float*)d_in[3];
  const float* rw     = (const float*)d_in[4];
  const float* rb     = (const float*)d_in[5];
  const float* w1     = (const float*)d_in[6];
  const float* b1     = (const float*)d_in[7];
  const float* dw     = (const float*)d_in[8];
  const float* bdw    = (const float*)d_in[9];
  const float* w2     = (const float*)d_in[10];
  const float* b2     = (const float*)d_in[11];
  const float* pw     = (const float*)d_in[12];
  const float* pb     = (const float*)d_in[13];
  float* out = (float*)d_out;

  char* base = (char*)d_ws;
  size_t off = 0;
  auto alloc = [&](size_t bytes)->void* {
    void* p = base + off;
    off = (off + bytes + 255) & ~(size_t)255;
    return p;
  };
  unsigned short* xin  = (unsigned short*)alloc((size_t)BB*HW*CC*2);     // 32 MiB [b][p][c]
  unsigned short* t1   = (unsigned short*)alloc((size_t)BB*2*HW*CC*2);   // 64 MiB [bk][p][o]
  unsigned short* t3   = (unsigned short*)alloc((size_t)BB*2*HW*CC*2);   // 64 MiB [bk][p][c]
  unsigned short* w1b  = (unsigned short*)alloc((size_t)EE*CC*CC*2);
  unsigned short* w2p  = (unsigned short*)alloc((size_t)EE*CC*CC*2);
  unsigned short* w2s  = (unsigned short*)alloc((size_t)BB*2*CC*CC*2);
  float* feat_sum      = (float*)alloc(BB*CC*4);
  int*   eidx          = (int*)alloc(BB*2*4);
  float* wgt           = (float*)alloc(BB*2*4);
  float* bias_out      = (float*)alloc(BB*CC*4);

  hipMemsetAsync(feat_sum, 0, BB*CC*4, stream);

  k_ln<<<dim3(HW/LNP, BB), LNP, 0, stream>>>(x, gamma, beta, xin, feat_sum);
  k_prep<<<dim3(EE*CC), 128, 0, stream>>>(pw, w2, w1, w2p, w1b);
  k_router<<<dim3(1), 256, 0, stream>>>(feat_sum, prompt, rw, rb, b2, pw, pb,
                                        eidx, wgt, bias_out);
  k_scalew2<<<dim3(CC*CC/256, BB*2), 256, 0, stream>>>(w2p, eidx, wgt, w2s);
  k_gemm1<<<dim3(HW/(32*PT1), BB*2), 256, 0, stream>>>(xin, w1b, b1, eidx, t1);
  k_dw<<<dim3(HH, BB*2), 256, 0, stream>>>(t1, dw, bdw, eidx, t3);
  k_gemm2<<<dim3(HW/(32*PT2), BB), 256, 0, stream>>>(t3, w2s, bias_out, x, out);
}

// Round 9
// 326.507 us; speedup vs baseline: 2.7925x; 1.0982x over previous
//
#include <hip/hip_runtime.h>
#include <hip/hip_bf16.h>

#define BB 8
#define CC 128
#define HH 128
#define WW 128
#define HW (HH*WW)
#define EE 4
#define EPSL 1e-6f
#define PT1 8
#define LNP 128

typedef __attribute__((ext_vector_type(8))) short bf16x8;
typedef __attribute__((ext_vector_type(4))) float f32x4;

__device__ inline float b2f(unsigned short u){
  union { unsigned int i; float f; } v; v.i = ((unsigned int)u)<<16; return v.f;
}
__device__ inline unsigned short f2b(float f){
  union { float f; unsigned int i; } v; v.f = f;
  unsigned int x = v.i;
  return (unsigned short)((x + 0x7fffu + ((x>>16)&1u)) >> 16);
}
// LDS swizzle for [px][c] bf16 tiles (256B rows): keeps 16B alignment,
// <=2-way banks on both dw-write (px uniform mod 8) and b128-read (px=lr).
__device__ inline int swz(int px, int cbyte){
  return cbyte ^ ((((px)&7) ^ (((px)>>3)&3)) << 4);
}

// ---- K1: LayerNorm over C per pixel; xin [b][p][c] bf16, coalesced via LDS tile
__global__ __launch_bounds__(128) void k_ln(
    const float* __restrict__ x, const float* __restrict__ gamma,
    const float* __restrict__ beta, unsigned short* __restrict__ xin) {
  int b = blockIdx.y;
  int p0 = blockIdx.x*LNP;
  int tid = threadIdx.x;
  const float* xb = x + (size_t)b*CC*HW + p0 + tid;
  float s=0.f, s2=0.f;
  for (int c=0;c<CC;c++){ float v = xb[(size_t)c*HW]; s+=v; s2+=v*v; }
  float mu = s*(1.f/CC);
  float var = s2*(1.f/CC) - mu*mu;
  float rs = rsqrtf(var + EPSL);

  __shared__ unsigned short tile[LNP][CC+8];
  for (int c0=0;c0<CC;c0+=8){
    union { bf16x8 v; unsigned short s[8]; } pk;
    #pragma unroll
    for (int j=0;j<8;j++){
      float v = (xb[(size_t)(c0+j)*HW]-mu)*rs*gamma[c0+j]+beta[c0+j];
      pk.s[j]=f2b(v);
    }
    *(bf16x8*)&tile[tid][c0] = pk.v;
  }
  __syncthreads();
  unsigned short* xo = xin + ((size_t)b*HW + p0)*CC;
  #pragma unroll
  for (int it=0; it<16; ++it){
    int i = it*LNP + tid;
    int pr = i>>4, ck = (i&15)*8;
    *(bf16x8*)(xo + (size_t)i*8) = *(bf16x8*)&tile[pr][ck];
  }
}

// ---- K1b: feat_sum[b][c] = sum_p xin[b][p][c]  (xin is L2/L3-resident) --------
__global__ __launch_bounds__(256) void k_feat(
    const unsigned short* __restrict__ xin, float* __restrict__ feat_sum) {
  int b = blockIdx.y;
  int g = blockIdx.x;            // 128 pixel-groups of 128 px
  int tid = threadIdx.x;
  int cg = (tid & 15) * 8;
  int po = tid >> 4;             // 16 pixel slots
  __shared__ float lfeat[CC];
  for (int c=tid;c<CC;c+=256) lfeat[c]=0.f;
  __syncthreads();
  const unsigned short* base = xin + ((size_t)b*HW + (size_t)g*128)*CC + cg;
  float acc[8] = {};
  #pragma unroll
  for (int i=0;i<8;i++){
    bf16x8 v = *(const bf16x8*)(base + (size_t)(i*16+po)*CC);
    #pragma unroll
    for (int j=0;j<8;j++) acc[j] += b2f((unsigned short)v[j]);
  }
  #pragma unroll
  for (int j=0;j<8;j++) atomicAdd(&lfeat[cg+j], acc[j]);
  __syncthreads();
  if (tid < CC) atomicAdd(&feat_sum[b*CC+tid], lfeat[tid]);
}

// ---- K2: router (1 block) ------------------------------------------------------
__global__ __launch_bounds__(256) void k_router(
    const float* __restrict__ feat_sum, const float* __restrict__ prompt,
    const float* __restrict__ rw, const float* __restrict__ rb,
    const float* __restrict__ b2, const float* __restrict__ pw,
    const float* __restrict__ pb,
    int* __restrict__ eidx, float* __restrict__ wgt, float* __restrict__ bias_out) {
  __shared__ float logits[BB][EE];
  __shared__ float gate[BB][EE];
  __shared__ float cb[BB][CC];
  int t = threadIdx.x;
  if (t < BB*EE) {
    int b = t/EE, e = t%EE;
    float acc = rb[e];
    for (int c=0;c<CC;c++) acc += (feat_sum[b*CC+c]*(1.f/HW))*rw[c*EE+e];
    for (int c=0;c<CC;c++) acc += prompt[b*CC+c]*rw[(CC+c)*EE+e];
    logits[b][e]=acc;
  }
  __syncthreads();
  if (t < BB) {
    int b=t;
    float m=-1e30f;
    for(int e=0;e<EE;e++) m=fmaxf(m,logits[b][e]);
    float s=0.f, pr[EE];
    for(int e=0;e<EE;e++){ pr[e]=__expf(logits[b][e]-m); s+=pr[e]; }
    for(int e=0;e<EE;e++){ pr[e]/=s; gate[b][e]=0.f; }
    int i1=0; for(int e=1;e<EE;e++) if (pr[e]>pr[i1]) i1=e;
    int i2=-1; for(int e=0;e<EE;e++){ if(e==i1) continue; if(i2<0||pr[e]>pr[i2]) i2=e; }
    eidx[b*2]=i1; eidx[b*2+1]=i2;
    wgt[b*2]=pr[i1]; wgt[b*2+1]=pr[i2];
    gate[b][i1]=pr[i1]; gate[b][i2]=pr[i2];
  }
  __syncthreads();
  for (int i=t;i<BB*CC;i+=256){
    int b=i/CC, c=i%CC;
    float a=0.f;
    for(int e=0;e<EE;e++) a += gate[b][e]*b2[e*CC+c];
    cb[b][c]=a;
  }
  __syncthreads();
  for (int i=t;i<BB*CC;i+=256){
    int b=i/CC, o=i%CC;
    float a=pb[o];
    for (int c=0;c<CC;c++) a += pw[o*CC+c]*cb[b][c];
    bias_out[b*CC+o]=a;
  }
}

// ---- K3: prep: w2p[e] = bf16(pw @ w2[e]); w1b[e] = bf16(w1[e]) -----------------
__global__ __launch_bounds__(128) void k_prep(
    const float* __restrict__ pw, const float* __restrict__ w2,
    const float* __restrict__ w1,
    unsigned short* __restrict__ w2p, unsigned short* __restrict__ w1b){
  int eo = blockIdx.x; int e = eo/CC, o = eo%CC;
  int c = threadIdx.x;
  float a=0.f;
  for (int m=0;m<CC;m++) a += pw[o*CC+m]*w2[((size_t)e*CC+m)*CC+c];
  w2p[((size_t)e*CC+o)*CC+c] = f2b(a);
  w1b[((size_t)e*CC+o)*CC+c] = f2b(w1[((size_t)e*CC+o)*CC+c]);
}

// ---- K3b: w2s[bk] = bf16(wgt[bk] * w2p[e[bk]]) ---------------------------------
__global__ __launch_bounds__(256) void k_scalew2(
    const unsigned short* __restrict__ w2p, const int* __restrict__ eidx,
    const float* __restrict__ wgt, unsigned short* __restrict__ w2s){
  int bk = blockIdx.y;
  int e = eidx[bk]; float wv = wgt[bk];
  int i = blockIdx.x*256 + threadIdx.x;
  const unsigned short* src = w2p + (size_t)e*CC*CC;
  w2s[(size_t)bk*CC*CC + i] = f2b(wv * b2f(src[i]));
}

// ---- K4: GEMM1 (MFMA bf16): t1[bk][p][o] = w1b[e] @ xin[b] + b1[e] -------------
__global__ __launch_bounds__(256) void k_gemm1(
    const unsigned short* __restrict__ xin, const unsigned short* __restrict__ w1b,
    const float* __restrict__ b1, const int* __restrict__ eidx,
    unsigned short* __restrict__ t1) {
  int bk = blockIdx.y; int b = bk>>1; int e = eidx[bk];
  int wave = threadIdx.x>>6, lane = threadIdx.x&63;
  int lr = lane&15, lg = lane>>4;
  int ob = wave*32;
  const unsigned short* Ae = w1b + (size_t)e*CC*CC;
  bf16x8 A[2][4];
  #pragma unroll
  for (int of=0; of<2; of++)
    #pragma unroll
    for (int k0=0; k0<4; k0++)
      A[of][k0] = *(const bf16x8*)(Ae + (size_t)(ob+of*16+lr)*CC + k0*32 + lg*8);
  float bs[2][4];
  #pragma unroll
  for (int of=0; of<2; of++)
    #pragma unroll
    for (int r=0; r<4; r++)
      bs[of][r] = b1[e*CC + ob + of*16 + lg*4 + r];

  int p_start = blockIdx.x * (32*PT1);
  const unsigned short* Xb = xin + ((size_t)b*HW + p_start)*CC;
  unsigned short* T = t1 + ((size_t)bk*HW + p_start)*CC;

  bf16x8 Ba[2][4], Bb[2][4];
  auto loadB = [&](bf16x8 (&Bf)[2][4], int tt){
    const unsigned short* Xt = Xb + (size_t)tt*32*CC;
    #pragma unroll
    for (int pf=0; pf<2; pf++)
      #pragma unroll
      for (int k0=0; k0<4; k0++)
        Bf[pf][k0] = *(const bf16x8*)(Xt + (size_t)(pf*16+lr)*CC + k0*32 + lg*8);
  };
  auto comp = [&](bf16x8 (&Bf)[2][4], int tt){
    f32x4 acc[2][2];
    #pragma unroll
    for (int of=0; of<2; of++){ acc[of][0]=(f32x4){0,0,0,0}; acc[of][1]=(f32x4){0,0,0,0}; }
    #pragma unroll
    for (int k0=0; k0<4; k0++)
      #pragma unroll
      for (int of=0; of<2; of++)
        #pragma unroll
        for (int pf=0; pf<2; pf++)
          acc[of][pf] = __builtin_amdgcn_mfma_f32_16x16x32_bf16(A[of][k0], Bf[pf][k0], acc[of][pf],0,0,0);
    unsigned short* Tt = T + (size_t)tt*32*CC;
    #pragma unroll
    for (int of=0; of<2; of++){
      int o0 = ob + of*16 + lg*4;
      #pragma unroll
      for (int pf=0; pf<2; pf++){
        union { unsigned long long u; unsigned short s[4]; } pk;
        #pragma unroll
        for (int r=0; r<4; r++) pk.s[r]=f2b(acc[of][pf][r]+bs[of][r]);
        *(unsigned long long*)(Tt + (size_t)(pf*16+lr)*CC + o0) = pk.u;
      }
    }
  };

  loadB(Ba, 0);
  #pragma unroll
  for (int t=0; t<PT1; t++){
    if ((t&1)==0){ if (t+1<PT1) loadB(Bb, t+1); comp(Ba, t); }
    else         { if (t+1<PT1) loadB(Ba, t+1); comp(Bb, t); }
  }
}

// ---- K5: FUSED dwconv3x3+GELU -> LDS -> GEMM2 + residual + bias ----------------
// Block = (row h, batch b). Phase A: dw for both experts into swizzled LDS tiles.
// Phase B: 4 waves (ob=wave*32) do MFMA with B-frags from LDS, write out.
__global__ __launch_bounds__(256) void k_dwg2(
    const unsigned short* __restrict__ t1, const float* __restrict__ dw,
    const float* __restrict__ bdw, const int* __restrict__ eidx,
    const unsigned short* __restrict__ w2s, const float* __restrict__ bias_out,
    const float* __restrict__ x, float* __restrict__ out) {
  int b = blockIdx.y;
  int h = blockIdx.x;
  int tid = threadIdx.x;

  __shared__ unsigned short t3s[2][HH*CC/HH*CC/CC];  // placeholder sizing below
  // real tiles:
  __shared__ unsigned short tile2[2][128*CC];        // 2 x 32KB
  __shared__ float skd2[2][CC*9];
  __shared__ float sbd2[2][CC];
  (void)t3s;

  int e0 = eidx[b*2], e1 = eidx[b*2+1];
  for (int i=tid; i<2*CC*9; i+=256){
    int kk = i/(CC*9), j = i%(CC*9);
    skd2[kk][j] = dw[(size_t)(kk? e1:e0)*CC*9 + j];
  }
  for (int i=tid; i<2*CC; i+=256){
    int kk = i/CC, j = i%CC;
    sbd2[kk][j] = bdw[(kk? e1:e0)*CC + j];
  }
  __syncthreads();

  int cg = (tid & 15) * 8;
  int ws = (tid >> 4) * 8;

  #pragma unroll
  for (int kk=0; kk<2; kk++){
    float acc[8][8];
    #pragma unroll
    for (int px=0; px<8; px++)
      #pragma unroll
      for (int j=0; j<8; j++) acc[px][j] = sbd2[kk][cg+j];

    const unsigned short* rowbase = t1 + ((size_t)(b*2+kk)*HW + (size_t)h*WW)*CC + cg;
    #pragma unroll
    for (int dy=0; dy<3; dy++){
      int h2 = h + dy - 1;
      if (h2 < 0 || h2 >= HH) continue;
      const unsigned short* rp = rowbase + (size_t)(dy-1)*WW*CC;
      bf16x8 v[10];
      #pragma unroll
      for (int t=0; t<10; t++){
        int wc = ws + t - 1;
        if (wc >= 0 && wc < WW) v[t] = *(const bf16x8*)(rp + (size_t)wc*CC);
        else                    v[t] = (bf16x8){0,0,0,0,0,0,0,0};
      }
      #pragma unroll
      for (int dx=0; dx<3; dx++){
        float wk[8];
        #pragma unroll
        for (int j=0; j<8; j++) wk[j] = skd2[kk][(cg+j)*9 + dy*3 + dx];
        #pragma unroll
        for (int px=0; px<8; px++)
          #pragma unroll
          for (int j=0; j<8; j++)
            acc[px][j] += b2f((unsigned short)v[px+dx][j]) * wk[j];
      }
    }
    #pragma unroll
    for (int px=0; px<8; px++){
      union { bf16x8 v; unsigned short s[8]; } pk;
      #pragma unroll
      for (int j=0; j<8; j++){
        float a = acc[px][j];
        pk.s[j] = f2b(0.5f*a*(1.f+erff(a*0.70710678f)));
      }
      int p = ws + px;
      *(bf16x8*)((char*)&tile2[kk][0] + p*256 + swz(p, cg*2)) = pk.v;
    }
  }

  // A-regs + biases while LDS writes drain
  int wave = tid>>6, lane = tid&63;
  int lr = lane&15, lg = lane>>4;
  int ob = wave*32;
  bf16x8 A[2][2][4];
  #pragma unroll
  for (int kk=0; kk<2; kk++){
    const unsigned short* Ae = w2s + (size_t)(b*2+kk)*CC*CC;
    #pragma unroll
    for (int of=0; of<2; of++)
      #pragma unroll
      for (int k0=0; k0<4; k0++)
        A[kk][of][k0] = *(const bf16x8*)(Ae + (size_t)(ob+of*16+lr)*CC + k0*32 + lg*8);
  }
  float bo[2][4];
  #pragma unroll
  for (int of=0; of<2; of++)
    #pragma unroll
    for (int r=0; r<4; r++)
      bo[of][r] = bias_out[b*CC + ob + of*16 + lg*4 + r];

  __syncthreads();

  const float* xb = x + (size_t)b*CC*HW + (size_t)h*WW;
  float* obp = out + (size_t)b*CC*HW + (size_t)h*WW;

  #pragma unroll
  for (int tt=0; tt<4; tt++){
    f32x4 acc[2][2];
    #pragma unroll
    for (int of=0; of<2; of++){ acc[of][0]=(f32x4){0,0,0,0}; acc[of][1]=(f32x4){0,0,0,0}; }
    #pragma unroll
    for (int kk=0; kk<2; kk++){
      #pragma unroll
      for (int k0=0; k0<4; k0++){
        int cb = k0*64 + lg*16;
        bf16x8 B0 = *(bf16x8*)((char*)&tile2[kk][0] + (tt*32+lr   )*256 + swz(tt*32+lr,    cb));
        bf16x8 B1 = *(bf16x8*)((char*)&tile2[kk][0] + (tt*32+16+lr)*256 + swz(tt*32+16+lr, cb));
        #pragma unroll
        for (int of=0; of<2; of++){
          acc[of][0] = __builtin_amdgcn_mfma_f32_16x16x32_bf16(A[kk][of][k0], B0, acc[of][0],0,0,0);
          acc[of][1] = __builtin_amdgcn_mfma_f32_16x16x32_bf16(A[kk][of][k0], B1, acc[of][1],0,0,0);
        }
      }
    }
    #pragma unroll
    for (int of=0; of<2; of++){
      int o0 = ob + of*16 + lg*4;
      #pragma unroll
      for (int r=0; r<4; r++){
        #pragma unroll
        for (int pf=0; pf<2; pf++){
          size_t idx = (size_t)(o0+r)*HW + tt*32 + pf*16 + lr;
          obp[idx] = xb[idx] + acc[of][pf][r] + bo[of][r];
        }
      }
    }
  }
}

extern "C" void kernel_launch(void* const* d_in, const int* in_sizes, int n_in,
                              void* d_out, int out_size, void* d_ws, size_t ws_size,
                              hipStream_t stream) {
  const float* x      = (const float*)d_in[0];
  const float* prompt = (const float*)d_in[1];
  const float* gamma  = (const float*)d_in[2];
  const float* beta   = (const float*)d_in[3];
  const float* rw     = (const float*)d_in[4];
  const float* rb     = (const float*)d_in[5];
  const float* w1     = (const float*)d_in[6];
  const float* b1     = (const float*)d_in[7];
  const float* dw     = (const float*)d_in[8];
  const float* bdw    = (const float*)d_in[9];
  const float* w2     = (const float*)d_in[10];
  const float* b2     = (const float*)d_in[11];
  const float* pw     = (const float*)d_in[12];
  const float* pb     = (const float*)d_in[13];
  float* out = (float*)d_out;

  char* base = (char*)d_ws;
  size_t off = 0;
  auto alloc = [&](size_t bytes)->void* {
    void* p = base + off;
    off = (off + bytes + 255) & ~(size_t)255;
    return p;
  };
  unsigned short* xin  = (unsigned short*)alloc((size_t)BB*HW*CC*2);     // 32 MiB [b][p][c]
  unsigned short* t1   = (unsigned short*)alloc((size_t)BB*2*HW*CC*2);   // 64 MiB [bk][p][o]
  unsigned short* w1b  = (unsigned short*)alloc((size_t)EE*CC*CC*2);
  unsigned short* w2p  = (unsigned short*)alloc((size_t)EE*CC*CC*2);
  unsigned short* w2s  = (unsigned short*)alloc((size_t)BB*2*CC*CC*2);
  float* feat_sum      = (float*)alloc(BB*CC*4);
  int*   eidx          = (int*)alloc(BB*2*4);
  float* wgt           = (float*)alloc(BB*2*4);
  float* bias_out      = (float*)alloc(BB*CC*4);

  hipMemsetAsync(feat_sum, 0, BB*CC*4, stream);

  k_ln<<<dim3(HW/LNP, BB), LNP, 0, stream>>>(x, gamma, beta, xin);
  k_feat<<<dim3(128, BB), 256, 0, stream>>>(xin, feat_sum);
  k_prep<<<dim3(EE*CC), 128, 0, stream>>>(pw, w2, w1, w2p, w1b);
  k_router<<<dim3(1), 256, 0, stream>>>(feat_sum, prompt, rw, rb, b2, pw, pb,
                                        eidx, wgt, bias_out);
  k_scalew2<<<dim3(CC*CC/256, BB*2), 256, 0, stream>>>(w2p, eidx, wgt, w2s);
  k_gemm1<<<dim3(HW/(32*PT1), BB*2), 256, 0, stream>>>(xin, w1b, b1, eidx, t1);
  k_dwg2<<<dim3(HH, BB), 256, 0, stream>>>(t1, dw, bdw, eidx, w2s, bias_out, x, out);
}